// Round 1
// 853.075 us; speedup vs baseline: 1.0958x; 1.0958x over previous
//
#include <hip/hip_runtime.h>
#include <math.h>

namespace {

constexpr int N = 10000;
constexpr int K = 16;
constexpr int JT = 256;            // j-chunk staged in LDS (16 KB)
constexpr int RPB = 8;             // rows per block = 4 waves x 2 rows/lane
constexpr int TILES = N / RPB;     // 1250 (exact)
constexpr int JU = 4;              // j-units (column split)
constexpr int JX = N / JU;         // 2500 columns per unit (exact)
constexpr int NCH = (JX + JT - 1) / JT;  // 10 chunks, last clen = 196

// ws layout: bytes [0,8) = double sum(adj); floats [4..20) = cluster_size[16]
// d_out layout: [0]=clu_loss  [1..1+N)= -struct  [1+N..1+2N)= -att  [1+2N..1+3N)= -(s+a)
// scl_main atomically accumulates UNNORMALIZED partials into d_out sections 1,2
// (pre-zeroed); finalize normalizes in place and computes totals + clu_loss.

__global__ __launch_bounds__(256, 6)
void scl_main(const float* __restrict__ adj, const float* __restrict__ att,
              const float* __restrict__ outm, float* __restrict__ ws,
              float* __restrict__ d_out) {
  // output chunk transposed into 16 per-k planes; lane reads planes[k][jl..jl+3]
  // as float4 -> contiguous ds_read_b128.
  __shared__ float planes[K][JT];
  __shared__ float rred[4];

  const int bx = blockIdx.x;
  const int m = (bx >= TILES * JU) ? 1 : 0;          // 0 = adj, 1 = att
  const int t = bx - m * TILES * JU;
  const int ju = t / TILES;                          // j-unit 0..3
  const int tile = t - ju * TILES;                   // row tile 0..1249
  const float* __restrict__ A = m ? att : adj;
  const int wave = threadIdx.x >> 6;
  const int lane = threadIdx.x & 63;
  const int r0 = tile * RPB + wave * 2;              // 2 rows per wave
  const int j0 = ju * JX;

  float acc0[K], acc1[K];
#pragma unroll
  for (int k = 0; k < K; ++k) { acc0[k] = 0.f; acc1[k] = 0.f; }
  float rsum = 0.f;
  const float* __restrict__ Ar = A + (size_t)r0 * N + j0;

#pragma unroll 1
  for (int c = 0; c < NCH; ++c) {
    const int jb = j0 + c * JT;
    const int rem = JX - c * JT;
    const int clen = rem < JT ? rem : JT;            // 256 or 196 (multiple of 4)

    // Stage out[jb .. jb+clen) -> planes (transposed). Coalesced float4 global
    // reads (L2-hot: same-ju neighbor blocks share this window).
    for (int idx = threadIdx.x; idx < (clen << 2); idx += 256) {
      const int jj = idx >> 2;
      const int q = idx & 3;
      const float4 v = *(const float4*)(outm + ((size_t)(jb + jj) << 4) + (q << 2));
      planes[q * 4 + 0][jj] = v.x;
      planes[q * 4 + 1][jj] = v.y;
      planes[q * 4 + 2][jj] = v.z;
      planes[q * 4 + 3][jj] = v.w;
    }
    __syncthreads();

    const int jl = lane << 2;
    if (jl < clen) {
      const float* p = Ar + c * JT + jl;
      const float4 a0 = *(const float4*)(p);
      const float4 a1 = *(const float4*)(p + N);
      if (m == 0)
        rsum += (a0.x + a0.y + a0.z + a0.w) + (a1.x + a1.y + a1.z + a1.w);
#pragma unroll
      for (int k = 0; k < K; ++k) {
        const float4 o = *(const float4*)&planes[k][jl];
        acc0[k] += a0.x * o.x + a0.y * o.y + a0.z * o.z + a0.w * o.w;
        acc1[k] += a1.x * o.x + a1.y * o.y + a1.z * o.z + a1.w * o.w;
      }
    }
    __syncthreads();
  }

  // Epilogue: partial struct/att contribution of this j-unit for rows r0, r0+1:
  // dot with out rows first, then lane-reduce, then atomic accumulate.
  float p0 = 0.f, p1 = 0.f;
  const float* o0 = outm + (size_t)r0 * K;
#pragma unroll
  for (int k = 0; k < K; ++k) {
    p0 += o0[k] * acc0[k];
    p1 += o0[K + k] * acc1[k];
  }
#pragma unroll
  for (int off = 32; off >= 1; off >>= 1) {
    p0 += __shfl_xor(p0, off, 64);
    p1 += __shfl_xor(p1, off, 64);
    rsum += __shfl_xor(rsum, off, 64);
  }
  if (lane == 0) {
    atomicAdd(&d_out[1 + m * N + r0], p0);
    atomicAdd(&d_out[1 + m * N + r0 + 1], p1);
    rred[wave] = rsum;
  }
  __syncthreads();
  if (threadIdx.x == 0 && m == 0) {
    const double rb = (double)rred[0] + (double)rred[1] +
                      (double)rred[2] + (double)rred[3];
    atomicAdd((double*)ws, rb);   // ws bytes [0,8) = double sum(adj)
  }
}

// cluster_size[k] = sum_i out[i,k]. Thread t: k = t&15, row group g = t>>4.
__global__ void scl_colsum(const float* __restrict__ outm, float* __restrict__ ws) {
  __shared__ float red[16][17];
  const int k = threadIdx.x & 15;
  const int g = threadIdx.x >> 4;  // 0..15
  float acc = 0.f;
  for (int r = blockIdx.x * 16 + g; r < N; r += gridDim.x * 16)
    acc += outm[(size_t)r * K + k];
  red[g][k] = acc;
  __syncthreads();
  if (threadIdx.x < 16) {
    float s = 0.f;
#pragma unroll
    for (int gg = 0; gg < 16; ++gg) s += red[gg][threadIdx.x];
    atomicAdd(&ws[4 + threadIdx.x], s);
  }
}

// Single block: sum the unnormalized sections, then normalize in place.
__global__ void scl_finalize(float* __restrict__ d_out, const float* __restrict__ ws) {
  __shared__ float red[1024];
  const double S = *(const double*)ws;
  const float inv = (float)(1.0 / S);

  float tsum = 0.f;
  for (int i = threadIdx.x; i < 2 * N; i += 1024) tsum += d_out[1 + i];
  red[threadIdx.x] = tsum;
  __syncthreads();
#pragma unroll
  for (int s = 512; s > 0; s >>= 1) {
    if (threadIdx.x < s) red[threadIdx.x] += red[threadIdx.x + s];
    __syncthreads();
  }

  for (int i = threadIdx.x; i < N; i += 1024) {
    const float su = d_out[1 + i];
    const float au = d_out[1 + N + i];
    d_out[1 + i] = -su * inv;
    d_out[1 + N + i] = -au * inv;
    d_out[1 + 2 * N + i] = -(su + au) * inv;
  }
  if (threadIdx.x == 0) {
    float cs2 = 0.f;
#pragma unroll
    for (int k = 0; k < K; ++k) cs2 += ws[4 + k] * ws[4 + k];
    const float reg = sqrtf(cs2) / (float)N * 4.0f - 1.0f;  // sqrt(K)=4
    d_out[0] = -(red[0] * inv - reg);
  }
}

}  // namespace

extern "C" void kernel_launch(void* const* d_in, const int* in_sizes, int n_in,
                              void* d_out, int out_size, void* d_ws, size_t ws_size,
                              hipStream_t stream) {
  const float* adj  = (const float*)d_in[0];
  const float* att  = (const float*)d_in[1];
  const float* outm = (const float*)d_in[2];
  float* out = (float*)d_out;
  float* ws = (float*)d_ws;

  // Zero scalar workspace + the two atomic-accumulated output sections.
  hipMemsetAsync(d_ws, 0, 32 * sizeof(float), stream);
  hipMemsetAsync((char*)d_out + sizeof(float), 0, 2 * N * sizeof(float), stream);
  scl_colsum<<<32, 256, 0, stream>>>(outm, ws);
  scl_main<<<2 * TILES * JU, 256, 0, stream>>>(adj, att, outm, ws, out);
  scl_finalize<<<1, 1024, 0, stream>>>(out, ws);
}